// Round 3
// baseline (306.811 us; speedup 1.0000x reference)
//
#include <hip/hip_runtime.h>
#include <math.h>

#define BATCH 8
#define NN 64
#define DD 256
#define HH 64
#define HD 4

__device__ __forceinline__ float block_reduce_sum(float v, float* scratch) {
    for (int o = 32; o > 0; o >>= 1) v += __shfl_down(v, o, 64);
    int lane = threadIdx.x & 63, wid = threadIdx.x >> 6;
    if (lane == 0) scratch[wid] = v;
    __syncthreads();
    if (threadIdx.x == 0) scratch[0] = scratch[0] + scratch[1] + scratch[2] + scratch[3];
    __syncthreads();
    float r = scratch[0];
    __syncthreads();
    return r;
}

__device__ __forceinline__ float block_reduce_max(float v, float* scratch) {
    for (int o = 32; o > 0; o >>= 1) v = fmaxf(v, __shfl_down(v, o, 64));
    int lane = threadIdx.x & 63, wid = threadIdx.x >> 6;
    if (lane == 0) scratch[wid] = v;
    __syncthreads();
    if (threadIdx.x == 0) scratch[0] = fmaxf(fmaxf(scratch[0], scratch[1]), fmaxf(scratch[2], scratch[3]));
    __syncthreads();
    float r = scratch[0];
    __syncthreads();
    return r;
}

// Kernel 1: per-node GEMM (8 batches share one weight slice, since w is
// broadcast over batch) + buntanh.
// Grid: 768 blocks = wsel(3) x n(64) x col-quarter(4)  -> 3 blocks/CU.
// Each block computes out[b=0..7, n, 64 cols] reading a 64 KB weight slab.
__global__ __launch_bounds__(256) void gemv_act_kernel(
    const float* __restrict__ state,
    const float* __restrict__ w1,
    const float* __restrict__ w2,
    const float* __restrict__ w3,
    float* __restrict__ outP, float* __restrict__ outK, float* __restrict__ outQ)
{
    const float UNTANH = 0.6f;
    const float BSCALE = 1.8477590650225735f; // sqrt(2+sqrt(2))

    int blk  = blockIdx.x;            // 0..767
    int wsel = blk >> 8;              // 0,1,2
    int n    = (blk >> 2) & 63;
    int kq4  = blk & 3;               // column quarter
    const float* w = (wsel == 0 ? w1 : (wsel == 1 ? w2 : w3))
                     + (size_t)n * DD * DD + kq4 * 64;   // batch-0 slice
    float* out = (wsel == 0 ? outP : (wsel == 1 ? outK : outQ));

    __shared__ float  s[BATCH][DD];           // 8 KB
    __shared__ float4 red[16][BATCH][16];     // 32 KB

    int t = threadIdx.x;
    #pragma unroll
    for (int b = 0; b < BATCH; b++) s[b][t] = state[(size_t)b * NN * DD + n * DD + t];
    __syncthreads();

    int kq = t & 15;   // column quad within the 64-col slab: cols 4*kq..4*kq+3
    int jp = t >> 4;   // j phase 0..15

    float4 acc[BATCH];
    #pragma unroll
    for (int b = 0; b < BATCH; b++) acc[b] = make_float4(0.f, 0.f, 0.f, 0.f);

    #pragma unroll 4
    for (int j = jp; j < DD; j += 16) {
        float4 wv = *reinterpret_cast<const float4*>(w + (size_t)j * DD + kq * 4);
        #pragma unroll
        for (int b = 0; b < BATCH; b++) {
            float sj = s[b][j];
            acc[b].x += sj * wv.x;
            acc[b].y += sj * wv.y;
            acc[b].z += sj * wv.z;
            acc[b].w += sj * wv.w;
        }
    }
    #pragma unroll
    for (int b = 0; b < BATCH; b++) red[jp][b][kq] = acc[b];
    __syncthreads();

    // 128 float4 outputs (8 b x 16 quads), threads 0..127
    if (t < 128) {
        int b = t >> 4, q = t & 15;
        float4 r = make_float4(0.f, 0.f, 0.f, 0.f);
        #pragma unroll
        for (int ph = 0; ph < 16; ph++) {
            float4 a = red[ph][b][q];
            r.x += a.x; r.y += a.y; r.z += a.z; r.w += a.w;
        }
        r.x = (tanhf(r.x) + UNTANH * r.x) * BSCALE;
        r.y = (tanhf(r.y) + UNTANH * r.y) * BSCALE;
        r.z = (tanhf(r.z) + UNTANH * r.z) * BSCALE;
        r.w = (tanhf(r.w) + UNTANH * r.w) * BSCALE;
        *reinterpret_cast<float4*>(out + (size_t)b * NN * DD + n * DD + kq4 * 64 + q * 4) = r;
    }
}

// Kernel 2: per (b,h) attention + global RMS + sinkhorn(5) + threshold + PV + loss.
__global__ __launch_bounds__(256) void attn_kernel(
    const float* __restrict__ P, const float* __restrict__ Kt, const float* __restrict__ Qr,
    const float* __restrict__ env, const float* __restrict__ state,
    float* __restrict__ acc)
{
    int b = blockIdx.x >> 6;
    int h = blockIdx.x & 63;

    __shared__ float  p[64][65];      // 16.6 KB (padded)
    __shared__ float4 qkv[3][64];     // Q, K, V rows ([n][4])
    __shared__ float  part[64][4];
    __shared__ float  scratch[8];

    int t = threadIdx.x;

    // load Q/K/V rows: wave 0 -> Q, wave 1 -> K, wave 2 -> V
    int which = t >> 6, nidx = t & 63;
    if (which < 3) {
        const float* src = which == 0 ? Qr : (which == 1 ? Kt : P);
        qkv[which][nidx] = *reinterpret_cast<const float4*>(src + (size_t)b * NN * DD + nidx * DD + h * HD);
    }
    __syncthreads();

    // raw_A: thread t owns row rn = t>>2, cols [16*mq, 16*mq+16)
    int rn = t >> 2;
    int mq = t & 3;
    float4 qv = qkv[0][rn];
    float vals[16];
    float sumsq = 0.f, mymax = -1e30f;
    #pragma unroll
    for (int i = 0; i < 16; i++) {
        int m = mq * 16 + i;
        float4 kv = qkv[1][m];
        float x = (qv.x * kv.x + qv.y * kv.y + qv.z * kv.z + qv.w * kv.w) * 0.5f;
        vals[i] = x;
        sumsq += x * x;
        mymax = fmaxf(mymax, x);
    }
    float tot = block_reduce_sum(sumsq, scratch);
    float sc  = rsqrtf(tot / 4096.f + 1e-8f);
    float mx  = block_reduce_max(mymax, scratch) * sc;
    #pragma unroll
    for (int i = 0; i < 16; i++) {
        p[rn][mq * 16 + i] = expf(vals[i] * sc - mx);
    }
    __syncthreads();

    // Sinkhorn-Knopp, 5 iterations: row normalize then col normalize
    for (int it = 0; it < 5; it++) {
        float ps = 0.f;
        #pragma unroll
        for (int i = 0; i < 16; i++) ps += p[rn][mq * 16 + i];
        part[rn][mq] = ps;
        __syncthreads();
        float rinv = 1.f / (part[rn][0] + part[rn][1] + part[rn][2] + part[rn][3] + 1e-8f);
        #pragma unroll
        for (int i = 0; i < 16; i++) p[rn][mq * 16 + i] *= rinv;
        __syncthreads();

        float cs = 0.f;
        #pragma unroll
        for (int i = 0; i < 16; i++) cs += p[mq * 16 + i][rn];
        part[rn][mq] = cs;
        __syncthreads();
        float cinv = 1.f / (part[rn][0] + part[rn][1] + part[rn][2] + part[rn][3] + 1e-8f);
        #pragma unroll
        for (int i = 0; i < 16; i++) p[mq * 16 + i][rn] *= cinv;
        __syncthreads();
    }

    // threshold + PV: thread t owns (n2 = t>>2, d2 = t&3)
    int n2 = t >> 2, d2 = t & 3;
    float rv = 0.f;
    #pragma unroll
    for (int m = 0; m < 64; m++) {
        float a = p[n2][m];
        a = (a > 0.015625f) ? a : 0.f;   // 1/64
        float vv = ((const float*)&qkv[2][m])[d2];
        rv += a * vv;
    }

    // fused loss partials
    int kfull = h * HD + d2;
    float envv = 0.f, memv = 0.f;
    if (n2 < 4) {
        float dif = rv - env[b * 1024 + n2 * DD + kfull];
        envv = dif * dif;
    } else {
        float dif = rv - state[(size_t)b * NN * DD + n2 * DD + kfull];
        memv = dif * dif;
    }
    float esum = block_reduce_sum(envv, scratch);
    float msum = block_reduce_sum(memv, scratch);
    if (t == 0) {
        atomicAdd(&acc[0], esum);
        atomicAdd(&acc[1], msum);
    }
}

__global__ void finalize_kernel(const float* __restrict__ acc, float* __restrict__ out) {
    // loss_env = accE / (8*4*256); loss_mem = accM / (8*60*256)
    out[0] = acc[0] / 8192.f + 0.5f * (acc[1] / 122880.f);
}

extern "C" void kernel_launch(void* const* d_in, const int* in_sizes, int n_in,
                              void* d_out, int out_size, void* d_ws, size_t ws_size,
                              hipStream_t stream) {
    const float* env   = (const float*)d_in[0];
    const float* w1    = (const float*)d_in[1];
    const float* w2    = (const float*)d_in[2];
    const float* w3    = (const float*)d_in[3];
    const float* state = (const float*)d_in[4];
    float* out = (float*)d_out;

    float* acc  = (float*)d_ws;                         // 2 floats
    float* bufP = (float*)((char*)d_ws + 256);          // [B,N,D] each
    float* bufK = bufP + BATCH * NN * DD;
    float* bufQ = bufK + BATCH * NN * DD;

    hipMemsetAsync(acc, 0, 2 * sizeof(float), stream);
    gemv_act_kernel<<<dim3(768), dim3(256), 0, stream>>>(state, w1, w2, w3, bufP, bufK, bufQ);
    attn_kernel<<<dim3(BATCH * HH), dim3(256), 0, stream>>>(bufP, bufK, bufQ, env, state, acc);
    finalize_kernel<<<dim3(1), dim3(1), 0, stream>>>(acc, out);
}

// Round 6
// 295.442 us; speedup vs baseline: 1.0385x; 1.0385x over previous
//
#include <hip/hip_runtime.h>
#include <math.h>

#define BATCH 8
#define NN 64
#define DD 256
#define HH 64
#define HD 4

__device__ __forceinline__ float block_reduce_sum(float v, float* scratch) {
    for (int o = 32; o > 0; o >>= 1) v += __shfl_down(v, o, 64);
    int lane = threadIdx.x & 63, wid = threadIdx.x >> 6;
    if (lane == 0) scratch[wid] = v;
    __syncthreads();
    if (threadIdx.x == 0) scratch[0] = scratch[0] + scratch[1] + scratch[2] + scratch[3];
    __syncthreads();
    float r = scratch[0];
    __syncthreads();
    return r;
}

__device__ __forceinline__ float block_reduce_max(float v, float* scratch) {
    for (int o = 32; o > 0; o >>= 1) v = fmaxf(v, __shfl_down(v, o, 64));
    int lane = threadIdx.x & 63, wid = threadIdx.x >> 6;
    if (lane == 0) scratch[wid] = v;
    __syncthreads();
    if (threadIdx.x == 0) scratch[0] = fmaxf(fmaxf(scratch[0], scratch[1]), fmaxf(scratch[2], scratch[3]));
    __syncthreads();
    float r = scratch[0];
    __syncthreads();
    return r;
}

// Kernel 1: per-node GEMM (8 batches share one weight slice; w is broadcast
// over batch) + buntanh.  Grid: 768 = wsel(3) x n(64) x col-quarter(4).
// MLP fix: all 16 weight float4 loads are issued up-front into registers
// (64 VGPRs in flight) BEFORE the LDS state staging, so HBM latency
// overlaps the staging + barrier instead of serializing 4-at-a-time.
__global__ __launch_bounds__(256) void gemv_act_kernel(
    const float* __restrict__ state,
    const float* __restrict__ w1,
    const float* __restrict__ w2,
    const float* __restrict__ w3,
    float* __restrict__ outP, float* __restrict__ outK, float* __restrict__ outQ)
{
    const float UNTANH = 0.6f;
    const float BSCALE = 1.8477590650225735f; // sqrt(2+sqrt(2))

    int blk  = blockIdx.x;            // 0..767
    int wsel = blk >> 8;              // 0,1,2
    int n    = (blk >> 2) & 63;
    int kq4  = blk & 3;               // column quarter
    const float* w = (wsel == 0 ? w1 : (wsel == 1 ? w2 : w3))
                     + (size_t)n * DD * DD + kq4 * 64;   // batch-0 slice
    float* out = (wsel == 0 ? outP : (wsel == 1 ? outK : outQ));

    __shared__ float  s[BATCH][DD];           // 8 KB
    __shared__ float4 red[16][BATCH][16];     // 32 KB

    int t  = threadIdx.x;
    int kq = t & 15;   // column quad within the 64-col slab
    int jp = t >> 4;   // j phase 0..15

    // issue all 16 weight loads first (independent, 64 VGPRs in flight)
    float4 wv[16];
    #pragma unroll
    for (int i = 0; i < 16; i++) {
        int j = jp + 16 * i;
        wv[i] = *reinterpret_cast<const float4*>(w + (size_t)j * DD + kq * 4);
    }

    // state staging overlaps the weight-load latency
    #pragma unroll
    for (int b = 0; b < BATCH; b++) s[b][t] = state[(size_t)b * NN * DD + n * DD + t];
    __syncthreads();

    float4 acc[BATCH];
    #pragma unroll
    for (int b = 0; b < BATCH; b++) acc[b] = make_float4(0.f, 0.f, 0.f, 0.f);

    #pragma unroll
    for (int i = 0; i < 16; i++) {
        int j = jp + 16 * i;
        float4 wvv = wv[i];
        #pragma unroll
        for (int b = 0; b < BATCH; b++) {
            float sj = s[b][j];
            acc[b].x += sj * wvv.x;
            acc[b].y += sj * wvv.y;
            acc[b].z += sj * wvv.z;
            acc[b].w += sj * wvv.w;
        }
    }
    #pragma unroll
    for (int b = 0; b < BATCH; b++) red[jp][b][kq] = acc[b];
    __syncthreads();

    // 128 float4 outputs (8 b x 16 quads), threads 0..127
    if (t < 128) {
        int b = t >> 4, q = t & 15;
        float4 r = make_float4(0.f, 0.f, 0.f, 0.f);
        #pragma unroll
        for (int ph = 0; ph < 16; ph++) {
            float4 a = red[ph][b][q];
            r.x += a.x; r.y += a.y; r.z += a.z; r.w += a.w;
        }
        r.x = (tanhf(r.x) + UNTANH * r.x) * BSCALE;
        r.y = (tanhf(r.y) + UNTANH * r.y) * BSCALE;
        r.z = (tanhf(r.z) + UNTANH * r.z) * BSCALE;
        r.w = (tanhf(r.w) + UNTANH * r.w) * BSCALE;
        *reinterpret_cast<float4*>(out + (size_t)b * NN * DD + n * DD + kq4 * 64 + q * 4) = r;
    }
}

// Kernel 2: per (b,h) attention + global RMS + sinkhorn(5) + threshold + PV
// + loss partials (written per-block; no atomics, no memset needed).
__global__ __launch_bounds__(256) void attn_kernel(
    const float* __restrict__ P, const float* __restrict__ Kt, const float* __restrict__ Qr,
    const float* __restrict__ env, const float* __restrict__ state,
    float* __restrict__ pacc)   // [2][512]
{
    int b = blockIdx.x >> 6;
    int h = blockIdx.x & 63;

    __shared__ float  p[64][65];      // padded
    __shared__ float4 qkv[3][64];     // Q, K, V rows ([n][4])
    __shared__ float  part[64][4];
    __shared__ float  scratch[8];

    int t = threadIdx.x;

    int which = t >> 6, nidx = t & 63;
    if (which < 3) {
        const float* src = which == 0 ? Qr : (which == 1 ? Kt : P);
        qkv[which][nidx] = *reinterpret_cast<const float4*>(src + (size_t)b * NN * DD + nidx * DD + h * HD);
    }
    __syncthreads();

    // raw_A: thread t owns row rn = t>>2, cols [16*mq, 16*mq+16)
    int rn = t >> 2;
    int mq = t & 3;
    float4 qv = qkv[0][rn];
    float vals[16];
    float sumsq = 0.f, mymax = -1e30f;
    #pragma unroll
    for (int i = 0; i < 16; i++) {
        int m = mq * 16 + i;
        float4 kv = qkv[1][m];
        float x = (qv.x * kv.x + qv.y * kv.y + qv.z * kv.z + qv.w * kv.w) * 0.5f;
        vals[i] = x;
        sumsq += x * x;
        mymax = fmaxf(mymax, x);
    }
    float tot = block_reduce_sum(sumsq, scratch);
    float sc  = rsqrtf(tot / 4096.f + 1e-8f);
    float mx  = block_reduce_max(mymax, scratch) * sc;
    #pragma unroll
    for (int i = 0; i < 16; i++) {
        p[rn][mq * 16 + i] = expf(vals[i] * sc - mx);
    }
    __syncthreads();

    // Sinkhorn-Knopp, 5 iterations: row normalize then col normalize
    for (int it = 0; it < 5; it++) {
        float ps = 0.f;
        #pragma unroll
        for (int i = 0; i < 16; i++) ps += p[rn][mq * 16 + i];
        part[rn][mq] = ps;
        __syncthreads();
        float rinv = 1.f / (part[rn][0] + part[rn][1] + part[rn][2] + part[rn][3] + 1e-8f);
        #pragma unroll
        for (int i = 0; i < 16; i++) p[rn][mq * 16 + i] *= rinv;
        __syncthreads();

        float cs = 0.f;
        #pragma unroll
        for (int i = 0; i < 16; i++) cs += p[mq * 16 + i][rn];
        part[rn][mq] = cs;
        __syncthreads();
        float cinv = 1.f / (part[rn][0] + part[rn][1] + part[rn][2] + part[rn][3] + 1e-8f);
        #pragma unroll
        for (int i = 0; i < 16; i++) p[mq * 16 + i][rn] *= cinv;
        __syncthreads();
    }

    // threshold + PV: thread t owns (n2 = t>>2, d2 = t&3)
    int n2 = t >> 2, d2 = t & 3;
    float rv = 0.f;
    #pragma unroll
    for (int m = 0; m < 64; m++) {
        float a = p[n2][m];
        a = (a > 0.015625f) ? a : 0.f;   // 1/64
        float vv = ((const float*)&qkv[2][m])[d2];
        rv += a * vv;
    }

    // fused loss partials
    int kfull = h * HD + d2;
    float envv = 0.f, memv = 0.f;
    if (n2 < 4) {
        float dif = rv - env[b * 1024 + n2 * DD + kfull];
        envv = dif * dif;
    } else {
        float dif = rv - state[(size_t)b * NN * DD + n2 * DD + kfull];
        memv = dif * dif;
    }
    float esum = block_reduce_sum(envv, scratch);
    float msum = block_reduce_sum(memv, scratch);
    if (t == 0) {
        pacc[blockIdx.x]       = esum;
        pacc[512 + blockIdx.x] = msum;
    }
}

__global__ __launch_bounds__(256) void finalize_kernel(
    const float* __restrict__ pacc, float* __restrict__ out)
{
    __shared__ float scratch[8];
    int t = threadIdx.x;
    float e = pacc[t] + pacc[t + 256];
    float m = pacc[512 + t] + pacc[512 + t + 256];
    float esum = block_reduce_sum(e, scratch);
    float msum = block_reduce_sum(m, scratch);
    if (t == 0) {
        // loss_env = E / (8*4*256); loss_mem = M / (8*60*256)
        out[0] = esum / 8192.f + 0.5f * (msum / 122880.f);
    }
}

extern "C" void kernel_launch(void* const* d_in, const int* in_sizes, int n_in,
                              void* d_out, int out_size, void* d_ws, size_t ws_size,
                              hipStream_t stream) {
    const float* env   = (const float*)d_in[0];
    const float* w1    = (const float*)d_in[1];
    const float* w2    = (const float*)d_in[2];
    const float* w3    = (const float*)d_in[3];
    const float* state = (const float*)d_in[4];
    float* out = (float*)d_out;

    float* bufP = (float*)d_ws;                         // [B,N,D] each
    float* bufK = bufP + BATCH * NN * DD;
    float* bufQ = bufK + BATCH * NN * DD;
    float* pacc = bufQ + BATCH * NN * DD;               // [2][512]

    gemv_act_kernel<<<dim3(768), dim3(256), 0, stream>>>(state, w1, w2, w3, bufP, bufK, bufQ);
    attn_kernel<<<dim3(BATCH * HH), dim3(256), 0, stream>>>(bufP, bufK, bufQ, env, state, pacc);
    finalize_kernel<<<dim3(1), dim3(256), 0, stream>>>(pacc, out);
}